// Round 1
// baseline (74.719 us; speedup 1.0000x reference)
//
#include <hip/hip_runtime.h>
#include <math.h>

#define NCAND 75
#define NBT 8
#define NC 3
#define IMH 192
#define IMW 192
#define CROP 174
#define CH0 9
#define CW0 9
#define NPIX (CROP * CROP)          // 30276
#define CHW (IMH * IMW)             // 36864
#define IMG_STRIDE (NC * CHW)
#define DENOM 90828.0f              // NC * CROP * CROP

// --- kernel 1: per-(cand,img[,split]) SAD partial sums ---------------------
// cand decomposition: flat = (ih*5 + iw)*3 + ir   (scale dim has size 1)
//   ash = -SHIFT_H[ih] = 2 - ih ; asw = 2 - iw ; arot = (1 - ir) * pi/180
template <int SPLIT, bool DIRECT>
__global__ __launch_bounds__(256) void sad_kernel(const float* __restrict__ img,
                                                  const float* __restrict__ ref,
                                                  float* __restrict__ out) {
    const int blk = blockIdx.x;
    const int ci  = blk / SPLIT;          // cand*NBT + im
    const int s   = blk % SPLIT;
    const int cand = ci / NBT;
    const int im   = ci % NBT;

    const int ih  = cand / 15;
    const int rem = cand % 15;
    const int iw  = rem / 3;
    const int ir  = rem % 3;

    const float ash  = (float)(2 - ih);
    const float asw  = (float)(2 - iw);
    const float arot = (float)(1 - ir) * 0.017453292519943295f;
    const float cr = cosf(arot);
    const float sr = sinf(arot);

    const float* ib = img + im * IMG_STRIDE;
    const float* rb = ref + im * IMG_STRIDE;

    float acc = 0.0f;
    for (int p = s * 256 + (int)threadIdx.x; p < NPIX; p += 256 * SPLIT) {
        const int i = p / CROP;
        const int j = p - i * CROP;
        const float xx = (float)(CW0 + j);
        const float yy = (float)(CH0 + i);
        // replicate reference fp32 op order (asc == 1)
        const float t1 = (xx + asw) - 95.5f;      // aw - cx
        const float t2 = (yy + ash) - 95.5f;      // ah - cy
        const float awr = cr * t1 - sr * t2;
        const float ahr = sr * t1 + cr * t2;
        const float gx = awr / 95.5f;
        const float gy = ahr / 95.5f;
        const float x = ((gx + 1.0f) * 192.0f - 1.0f) * 0.5f;
        const float y = ((gy + 1.0f) * 192.0f - 1.0f) * 0.5f;

        const float x0f = floorf(x);
        const float y0f = floorf(y);
        const float wx = x - x0f;
        const float wy = y - y0f;
        const int x0 = (int)x0f, y0 = (int)y0f;
        const int x1 = x0 + 1,  y1 = y0 + 1;

        float w00 = (1.0f - wx) * (1.0f - wy);
        float w10 = wx * (1.0f - wy);
        float w01 = (1.0f - wx) * wy;
        float w11 = wx * wy;

        const bool vx0 = (x0 >= 0) & (x0 < IMW);
        const bool vx1 = (x1 >= 0) & (x1 < IMW);
        const bool vy0 = (y0 >= 0) & (y0 < IMH);
        const bool vy1 = (y1 >= 0) & (y1 < IMH);
        if (!(vx0 & vy0)) w00 = 0.0f;
        if (!(vx1 & vy0)) w10 = 0.0f;
        if (!(vx0 & vy1)) w01 = 0.0f;
        if (!(vx1 & vy1)) w11 = 0.0f;

        const int xc0 = min(max(x0, 0), IMW - 1);
        const int xc1 = min(max(x1, 0), IMW - 1);
        const int yc0 = min(max(y0, 0), IMH - 1);
        const int yc1 = min(max(y1, 0), IMH - 1);

        const int a00 = yc0 * IMW + xc0;
        const int a10 = yc0 * IMW + xc1;
        const int a01 = yc1 * IMW + xc0;
        const int a11 = yc1 * IMW + xc1;
        const int ra  = (CH0 + i) * IMW + (CW0 + j);

#pragma unroll
        for (int c = 0; c < NC; ++c) {
            const float* cb = ib + c * CHW;
            const float v = w00 * cb[a00] + w10 * cb[a10] +
                            w01 * cb[a01] + w11 * cb[a11];
            acc += fabsf(v - rb[c * CHW + ra]);
        }
    }

    // block reduction: wave shuffle then LDS across 4 waves
#pragma unroll
    for (int off = 32; off > 0; off >>= 1) acc += __shfl_down(acc, off, 64);
    __shared__ float wsum[4];
    const int lane = threadIdx.x & 63;
    const int wid  = threadIdx.x >> 6;
    if (lane == 0) wsum[wid] = acc;
    __syncthreads();
    if (threadIdx.x == 0) {
        const float tot = wsum[0] + wsum[1] + wsum[2] + wsum[3];
        if (DIRECT) out[ci] = tot / DENOM;   // sad directly
        else        out[blk] = tot;          // raw partial sum
    }
}

// --- kernel 2a: reduce split partials -> sad, then per-image argmin --------
__global__ __launch_bounds__(640) void finalize_ws(const float* __restrict__ part,
                                                   float* __restrict__ out) {
    __shared__ float sads[NCAND * NBT];
    const int t = threadIdx.x;
    if (t < NCAND * NBT) {
        const float ssum = part[t * 4 + 0] + part[t * 4 + 1] +
                           part[t * 4 + 2] + part[t * 4 + 3];
        const float sv = ssum / DENOM;
        sads[t] = sv;
        out[t] = sv;
    }
    __syncthreads();
    if (t < NBT) {
        float best = sads[t];
        int bi = 0;
        for (int c2 = 1; c2 < NCAND; ++c2) {
            const float v = sads[c2 * NBT + t];
            if (v < best) { best = v; bi = c2; }   // strict <: first-min tie-break
        }
        const int i0 = bi / 15;
        const int r  = bi % 15;
        const int i1 = r / 3;
        const int i2 = r % 3;
        out[600 + 0 * NBT + t] = (float)i0;
        out[600 + 1 * NBT + t] = (float)i1;
        out[600 + 2 * NBT + t] = (float)i2;
        out[600 + 3 * NBT + t] = 0.0f;
    }
}

// --- kernel 2b: argmin only (sad already in d_out) -------------------------
__global__ __launch_bounds__(64) void finalize_direct(float* __restrict__ out) {
    const int t = threadIdx.x;
    if (t < NBT) {
        float best = out[t];
        int bi = 0;
        for (int c2 = 1; c2 < NCAND; ++c2) {
            const float v = out[c2 * NBT + t];
            if (v < best) { best = v; bi = c2; }
        }
        const int i0 = bi / 15;
        const int r  = bi % 15;
        const int i1 = r / 3;
        const int i2 = r % 3;
        out[600 + 0 * NBT + t] = (float)i0;
        out[600 + 1 * NBT + t] = (float)i1;
        out[600 + 2 * NBT + t] = (float)i2;
        out[600 + 3 * NBT + t] = 0.0f;
    }
}

extern "C" void kernel_launch(void* const* d_in, const int* in_sizes, int n_in,
                              void* d_out, int out_size, void* d_ws, size_t ws_size,
                              hipStream_t stream) {
    const float* img = (const float*)d_in[0];   // matrix (B,T,C,H,W)
    const float* ref = (const float*)d_in[1];   // reference_matrix
    float* out = (float*)d_out;

    if (ws_size >= (size_t)(NCAND * NBT * 4 * sizeof(float))) {
        float* part = (float*)d_ws;
        hipLaunchKernelGGL((sad_kernel<4, false>), dim3(NCAND * NBT * 4), dim3(256),
                           0, stream, img, ref, part);
        hipLaunchKernelGGL(finalize_ws, dim3(1), dim3(640), 0, stream, part, out);
    } else {
        hipLaunchKernelGGL((sad_kernel<1, true>), dim3(NCAND * NBT), dim3(256),
                           0, stream, img, ref, out);
        hipLaunchKernelGGL(finalize_direct, dim3(1), dim3(64), 0, stream, out);
    }
}